// Round 2
// baseline (73.966 us; speedup 1.0000x reference)
//
#include <hip/hip_runtime.h>

// Problem constants (match reference file).
#define M_ROWS 200000
#define D_DIM  256
#define NB     1024          // pass-1 blocks
#define TPB    256           // threads per block (4 waves)
#define WPB    (TPB / 64)    // waves per block
#define TOTAL_WAVES (NB * WPB)

// Pass 1: each wave processes whole rows. Lane l holds u[4l..4l+3] in regs.
// Per row: coalesced float4 load of keys row, wave-reduce dot, exp, then
// accumulate r * values row into per-lane float4 accumulator.
// Block-reduce 4 waves via LDS; write 256-float partial column-major into ws.
__global__ __launch_bounds__(TPB) void iv_pass1(
    const float* __restrict__ u,
    const float4* __restrict__ keys4,
    const float4* __restrict__ values4,
    float* __restrict__ partial)   // layout: partial[col * NB + block]
{
    const int lane  = threadIdx.x & 63;
    const int wid   = threadIdx.x >> 6;
    const int gwave = blockIdx.x * WPB + wid;

    // u fragment for this lane (D=256 = 64 lanes * 4 floats)
    const float4 u4 = ((const float4*)u)[lane];

    float4 acc = make_float4(0.f, 0.f, 0.f, 0.f);

    for (int row = gwave; row < M_ROWS; row += TOTAL_WAVES) {
        const float4 k4 = keys4[row * 64 + lane];
        float p = k4.x * u4.x + k4.y * u4.y + k4.z * u4.z + k4.w * u4.w;
        // 64-lane butterfly reduction -> every lane has the full dot product
        #pragma unroll
        for (int m = 32; m >= 1; m >>= 1)
            p += __shfl_xor(p, m, 64);
        const float r = __expf(p);
        const float4 v4 = values4[row * 64 + lane];
        acc.x += r * v4.x;
        acc.y += r * v4.y;
        acc.z += r * v4.z;
        acc.w += r * v4.w;
    }

    // Block reduction across the 4 waves. Lane l of wave w holds cols 4l..4l+3.
    __shared__ float lds[WPB][D_DIM];
    *(float4*)&lds[wid][lane * 4] = acc;
    __syncthreads();

    const int t = threadIdx.x;   // t == column index
    float s = lds[0][t] + lds[1][t] + lds[2][t] + lds[3][t];
    // Column-major so pass 2 reads each column's partials contiguously.
    partial[t * NB + blockIdx.x] = s;
}

// Pass 2: block c sums its 1024 partials (contiguous, L2-resident),
// writes out[256+c]; also passes through out[c] = u[c].
__global__ __launch_bounds__(256) void iv_pass2(
    const float* __restrict__ partial,
    const float* __restrict__ u,
    float* __restrict__ out)
{
    const int c = blockIdx.x;
    const int t = threadIdx.x;

    float s = 0.f;
    #pragma unroll
    for (int i = 0; i < NB / 256; ++i)
        s += partial[c * NB + i * 256 + t];

    #pragma unroll
    for (int m = 32; m >= 1; m >>= 1)
        s += __shfl_xor(s, m, 64);

    __shared__ float lds[256 / 64];
    if ((t & 63) == 0) lds[t >> 6] = s;
    __syncthreads();

    if (t == 0) {
        out[D_DIM + c] = lds[0] + lds[1] + lds[2] + lds[3];
        out[c] = u[c];
    }
}

extern "C" void kernel_launch(void* const* d_in, const int* in_sizes, int n_in,
                              void* d_out, int out_size, void* d_ws, size_t ws_size,
                              hipStream_t stream) {
    const float* u      = (const float*)d_in[0];   // (256,)
    const float* keys   = (const float*)d_in[1];   // (200000, 256)
    const float* values = (const float*)d_in[2];   // (200000, 256)
    float* out = (float*)d_out;                    // 512 floats: [u ; u_]
    float* partial = (float*)d_ws;                 // needs NB*256*4 = 1 MB

    iv_pass1<<<NB, TPB, 0, stream>>>(u, (const float4*)keys,
                                     (const float4*)values, partial);
    iv_pass2<<<D_DIM, 256, 0, stream>>>(partial, u, out);
}